// Round 2
// baseline (124.425 us; speedup 1.0000x reference)
//
#include <hip/hip_runtime.h>
#include <hip/hip_bf16.h>

// QuantizedConv2d: N=32, CIN=128, H=W=56, COUT=256, 3x3, pad=1 (zp=-3), stride 1.
// Strategy: implicit GEMM with mfma_i32_16x16x64_i8.
//   pack_x: NCHW int32 -> NHWC int8   (12.8 MB in d_ws)
//   pack_w: OIHW int32 -> fragment-ordered int8 [tap][kb][nfrag][lane][16B]
//   conv:   M = N*H*W = 100352 pixels, Ncols = 256 couts, K = 9*128.
// Exactness: conv is exactly integer (|acc| < 2^24), ref's round(acc+b)+b == acc+2b.
// Output: harness validates integer outputs as int32 -> store int32 (NOT float).

typedef __attribute__((ext_vector_type(4))) int i32x4;

#define NB_N 32
#define CIN 128
#define HH 56
#define WW 56
#define COUT 256
#define PIX_PER_IMG (HH*WW)              // 3136
#define X_IMG_BYTES (PIX_PER_IMG*CIN)    // 401408
#define TOTAL_PIX (NB_N*PIX_PER_IMG)     // 100352
#define XQ_BYTES (NB_N*X_IMG_BYTES)      // 12845056

// ---------------- pack_x: NCHW int32 -> NHWC int8 ----------------
__global__ __launch_bounds__(256) void pack_x_kernel(const int* __restrict__ x,
                                                     signed char* __restrict__ xq) {
    __shared__ signed char tile[WW * CIN];   // 7168 B, [w][c]
    int nh = blockIdx.x;                     // 0..N*H-1
    int n = nh / HH, h = nh - n * HH;
    const int* src = x + (size_t)n * X_IMG_BYTES + h * WW;  // (n, c, h, 0)
    for (int t = threadIdx.x; t < WW * CIN; t += 256) {
        int c = t / WW;
        int w = t - c * WW;
        int v = src[c * PIX_PER_IMG + w];
        tile[w * CIN + c] = (signed char)v;
    }
    __syncthreads();
    int* dst = (int*)(xq + (size_t)nh * (WW * CIN));
    const int* s4 = (const int*)tile;
    for (int t = threadIdx.x; t < (WW * CIN) / 4; t += 256)
        dst[t] = s4[t];
}

// ---------------- pack_w: OIHW int32 -> fragment-ordered int8 ----------------
// wq byte layout: frag f = (tap*2 + kb)*16 + nfrag, then lane*16 + j
// maps to weight[cout = nfrag*16 + (lane&15)][cin = kb*64 + (lane>>4)*16 + j][kh][kw]
__global__ __launch_bounds__(256) void pack_w_kernel(const int* __restrict__ w,
                                                     signed char* __restrict__ wq) {
    int idx = blockIdx.x * 256 + threadIdx.x;    // 0..18431
    if (idx >= 9 * 2 * 16 * 64) return;
    int lane = idx & 63;
    int fid = idx >> 6;            // 0..287
    int t = fid / 32;              // tap
    int rem = fid - t * 32;
    int kb = rem >> 4;
    int nf = rem & 15;
    int cout = nf * 16 + (lane & 15);
    int cinb = kb * 64 + (lane >> 4) * 16;
    int kh = t / 3, kw = t - kh * 3;
    union { signed char b[16]; i32x4 v; } u;
#pragma unroll
    for (int j = 0; j < 16; ++j) {
        int cin = cinb + j;
        u.b[j] = (signed char)w[((cout * CIN + cin) * 3 + kh) * 3 + kw];
    }
    *(i32x4*)(wq + (size_t)idx * 16) = u.v;
}

// ---------------- conv: implicit GEMM, 16x16x64 i8 MFMA ----------------
// grid = (TOTAL_PIX/128) * 4 blocks of 256 threads.
// block: mt = bid>>2 (128 pixels), nb = bid&3 (64 couts).
// wave wv owns pixels [mt*128 + wv*32, +32) as 2 M-frags; 4 N-frags of 16 couts.
__global__ __launch_bounds__(256) void conv_kernel(const signed char* __restrict__ xq,
                                                   const signed char* __restrict__ wq,
                                                   const int* __restrict__ bias,
                                                   const float* __restrict__ wscale,
                                                   int* __restrict__ out) {
    int bid = blockIdx.x;
    int mt = bid >> 2;
    int nb = bid & 3;
    int lane = threadIdx.x & 63;
    int wv = threadIdx.x >> 6;
    int pbase = mt * 128 + wv * 32;
    int row = lane & 15;
    int grp = lane >> 4;

    int p0 = pbase + row;          // M-frag 0 row pixel
    int p1 = p0 + 16;              // M-frag 1 row pixel (same image: 3136 % 32 == 0)
    int n = p0 / PIX_PER_IMG;
    int r0 = p0 - n * PIX_PER_IMG;
    int h0 = r0 / WW, w0 = r0 - h0 * WW;
    int r1 = p1 - n * PIX_PER_IMG;
    int h1 = r1 / WW, w1 = r1 - h1 * WW;

    const signed char* xbase = xq + (size_t)n * X_IMG_BYTES + grp * 16;

    i32x4 acc[2][4] = {};
    const i32x4 pad = {(int)0xFDFDFDFD, (int)0xFDFDFDFD, (int)0xFDFDFDFD, (int)0xFDFDFDFD};

#pragma unroll
    for (int t = 0; t < 9; ++t) {
        const int dh = t / 3 - 1, dw = t % 3 - 1;
        int ih0 = h0 + dh, iw0 = w0 + dw;
        int ih1 = h1 + dh, iw1 = w1 + dw;
        bool v0 = ((unsigned)ih0 < (unsigned)HH) && ((unsigned)iw0 < (unsigned)WW);
        bool v1 = ((unsigned)ih1 < (unsigned)HH) && ((unsigned)iw1 < (unsigned)WW);
        const i32x4* pa0 = (const i32x4*)(xbase + (ih0 * WW + iw0) * CIN);
        const i32x4* pa1 = (const i32x4*)(xbase + (ih1 * WW + iw1) * CIN);
        const signed char* wb = wq + ((size_t)((t * 2) * 16 + nb * 4)) * 1024 + lane * 16;
#pragma unroll
        for (int kb = 0; kb < 2; ++kb) {
            i32x4 a0 = v0 ? pa0[kb * 4] : pad;     // +kb*64 bytes
            i32x4 a1 = v1 ? pa1[kb * 4] : pad;
            i32x4 b0 = *(const i32x4*)(wb + (size_t)(kb * 16 + 0) * 1024);
            i32x4 b1 = *(const i32x4*)(wb + (size_t)(kb * 16 + 1) * 1024);
            i32x4 b2 = *(const i32x4*)(wb + (size_t)(kb * 16 + 2) * 1024);
            i32x4 b3 = *(const i32x4*)(wb + (size_t)(kb * 16 + 3) * 1024);
            acc[0][0] = __builtin_amdgcn_mfma_i32_16x16x64_i8(a0, b0, acc[0][0], 0, 0, 0);
            acc[0][1] = __builtin_amdgcn_mfma_i32_16x16x64_i8(a0, b1, acc[0][1], 0, 0, 0);
            acc[0][2] = __builtin_amdgcn_mfma_i32_16x16x64_i8(a0, b2, acc[0][2], 0, 0, 0);
            acc[0][3] = __builtin_amdgcn_mfma_i32_16x16x64_i8(a0, b3, acc[0][3], 0, 0, 0);
            acc[1][0] = __builtin_amdgcn_mfma_i32_16x16x64_i8(a1, b0, acc[1][0], 0, 0, 0);
            acc[1][1] = __builtin_amdgcn_mfma_i32_16x16x64_i8(a1, b1, acc[1][1], 0, 0, 0);
            acc[1][2] = __builtin_amdgcn_mfma_i32_16x16x64_i8(a1, b2, acc[1][2], 0, 0, 0);
            acc[1][3] = __builtin_amdgcn_mfma_i32_16x16x64_i8(a1, b3, acc[1][3], 0, 0, 0);
        }
    }

    // Epilogue: out_i = acc + 2*bias; f = out_i * (0.05*ws/0.1) + 5; rint; clamp; int32 store.
    // C/D frag: col (cout) = lane&15, row (pixel) = grp*4 + reg.
#pragma unroll
    for (int m = 0; m < 2; ++m) {
        int pix = pbase + m * 16 + grp * 4;          // pixel of reg 0
        int local = pix - n * PIX_PER_IMG;           // h*56 + w
        size_t obase = (size_t)n * (COUT * PIX_PER_IMG) + local;
#pragma unroll
        for (int j = 0; j < 4; ++j) {
            int cout = nb * 64 + j * 16 + row;
            float sc = wscale[cout] * 0.5f;          // 0.05/0.1 * ws
            int b2 = 2 * bias[cout];
            int4 v;
            int* vv = &v.x;
#pragma unroll
            for (int r = 0; r < 4; ++r) {
                int o = acc[m][j][r] + b2;
                float f = fmaf((float)o, sc, 5.0f);
                f = rintf(f);                         // RNE == jnp.round
                f = fminf(fmaxf(f, -128.0f), 127.0f);
                vv[r] = (int)f;
            }
            *(int4*)(out + obase + (size_t)cout * PIX_PER_IMG) = v;
        }
    }
}

extern "C" void kernel_launch(void* const* d_in, const int* in_sizes, int n_in,
                              void* d_out, int out_size, void* d_ws, size_t ws_size,
                              hipStream_t stream) {
    const int* x = (const int*)d_in[0];
    const int* w = (const int*)d_in[1];
    const int* bias = (const int*)d_in[2];
    const float* ws = (const float*)d_in[3];
    int* out = (int*)d_out;

    signed char* xq = (signed char*)d_ws;
    signed char* wq = xq + XQ_BYTES;          // 288 KB fragment-ordered weights

    pack_x_kernel<<<NB_N * HH, 256, 0, stream>>>(x, xq);
    pack_w_kernel<<<72, 256, 0, stream>>>(w, wq);
    conv_kernel<<<(TOTAL_PIX / 128) * 4, 256, 0, stream>>>(xq, wq, bias, ws, out);
}

// Round 4
// 121.293 us; speedup vs baseline: 1.0258x; 1.0258x over previous
//
#include <hip/hip_runtime.h>
#include <hip/hip_bf16.h>

// QuantizedConv2d: N=32, CIN=128, H=W=56, COUT=256, 3x3, pad=1 (zp=-3), stride 1.
// Implicit GEMM with mfma_i32_16x16x64_i8. Round 3: wave tile 64px x 64cout
// (acc[4][4]), launch_bounds(256,3) for VGPR headroom, nontemporal output
// stores via ext_vector i32x4 (HIP int4 struct not accepted by the builtin).

typedef __attribute__((ext_vector_type(4))) int i32x4;

#define NB_N 32
#define CIN 128
#define HH 56
#define WW 56
#define COUT 256
#define PIX_PER_IMG (HH*WW)              // 3136
#define X_IMG_BYTES (PIX_PER_IMG*CIN)    // 401408
#define TOTAL_PIX (NB_N*PIX_PER_IMG)     // 100352
#define XQ_BYTES (NB_N*X_IMG_BYTES)      // 12845056

// ---------------- pack_x: NCHW int32 -> NHWC int8 ----------------
__global__ __launch_bounds__(256) void pack_x_kernel(const int* __restrict__ x,
                                                     signed char* __restrict__ xq) {
    __shared__ signed char tile[WW * CIN];   // 7168 B, [w][c]
    int nh = blockIdx.x;                     // 0..N*H-1
    int n = nh / HH, h = nh - n * HH;
    const int* src = x + (size_t)n * X_IMG_BYTES + h * WW;  // (n, c, h, 0)
    for (int t = threadIdx.x; t < WW * CIN; t += 256) {
        int c = t / WW;
        int w = t - c * WW;
        int v = src[c * PIX_PER_IMG + w];
        tile[w * CIN + c] = (signed char)v;
    }
    __syncthreads();
    int* dst = (int*)(xq + (size_t)nh * (WW * CIN));
    const int* s4 = (const int*)tile;
    for (int t = threadIdx.x; t < (WW * CIN) / 4; t += 256)
        dst[t] = s4[t];
}

// ---------------- pack_w: OIHW int32 -> fragment-ordered int8 ----------------
// wq byte layout: frag f = (tap*2 + kb)*16 + nfrag, then lane*16 + j
// maps to weight[cout = nfrag*16 + (lane&15)][cin = kb*64 + (lane>>4)*16 + j][kh][kw]
__global__ __launch_bounds__(256) void pack_w_kernel(const int* __restrict__ w,
                                                     signed char* __restrict__ wq) {
    int idx = blockIdx.x * 256 + threadIdx.x;    // 0..18431
    if (idx >= 9 * 2 * 16 * 64) return;
    int lane = idx & 63;
    int fid = idx >> 6;            // 0..287
    int t = fid / 32;              // tap
    int rem = fid - t * 32;
    int kb = rem >> 4;
    int nf = rem & 15;
    int cout = nf * 16 + (lane & 15);
    int cinb = kb * 64 + (lane >> 4) * 16;
    int kh = t / 3, kw = t - kh * 3;
    union { signed char b[16]; i32x4 v; } u;
#pragma unroll
    for (int j = 0; j < 16; ++j) {
        int cin = cinb + j;
        u.b[j] = (signed char)w[((cout * CIN + cin) * 3 + kh) * 3 + kw];
    }
    *(i32x4*)(wq + (size_t)idx * 16) = u.v;
}

// ---------------- conv: implicit GEMM, 16x16x64 i8 MFMA ----------------
// grid = (TOTAL_PIX/256) * 4 blocks of 256 threads.
// block: mt = bid>>2 (256 pixels), nb = bid&3 (64 couts).
// wave wv owns 64 consecutive pixels (4 M-frags) x 64 couts (4 N-frags).
// (3136 % 64 == 0, so each wave's pixels stay within one image.)
__global__ __launch_bounds__(256, 3) void conv_kernel(const signed char* __restrict__ xq,
                                                      const signed char* __restrict__ wq,
                                                      const int* __restrict__ bias,
                                                      const float* __restrict__ wscale,
                                                      int* __restrict__ out) {
    int bid = blockIdx.x;
    int mt = bid >> 2;
    int nb = bid & 3;
    int lane = threadIdx.x & 63;
    int wv = threadIdx.x >> 6;
    int pbase = mt * 256 + wv * 64;
    int row = lane & 15;
    int grp = lane >> 4;

    int p0 = pbase + row;
    int n = p0 / PIX_PER_IMG;
    int local0 = p0 - n * PIX_PER_IMG;

    int hm[4], wm[4];
#pragma unroll
    for (int m = 0; m < 4; ++m) {
        int rm = local0 + m * 16;
        hm[m] = rm / WW;
        wm[m] = rm - hm[m] * WW;
    }

    const signed char* xbase = xq + (size_t)n * X_IMG_BYTES + grp * 16;

    i32x4 acc[4][4] = {};
    const i32x4 pad = {(int)0xFDFDFDFD, (int)0xFDFDFDFD, (int)0xFDFDFDFD, (int)0xFDFDFDFD};

#pragma unroll
    for (int t = 0; t < 9; ++t) {
        const int dh = t / 3 - 1, dw = t % 3 - 1;
        bool vm[4];
        const i32x4* pa[4];
#pragma unroll
        for (int m = 0; m < 4; ++m) {
            int ih = hm[m] + dh, iw = wm[m] + dw;
            vm[m] = ((unsigned)ih < (unsigned)HH) && ((unsigned)iw < (unsigned)WW);
            pa[m] = (const i32x4*)(xbase + (ih * WW + iw) * CIN);
        }
        const signed char* wb = wq + ((size_t)((t * 2) * 16 + nb * 4)) * 1024 + lane * 16;
#pragma unroll
        for (int kb = 0; kb < 2; ++kb) {
            i32x4 a[4], b[4];
#pragma unroll
            for (int m = 0; m < 4; ++m)
                a[m] = vm[m] ? pa[m][kb * 4] : pad;     // +kb*64 bytes
#pragma unroll
            for (int j = 0; j < 4; ++j)
                b[j] = *(const i32x4*)(wb + (size_t)(kb * 16 + j) * 1024);
#pragma unroll
            for (int m = 0; m < 4; ++m)
#pragma unroll
                for (int j = 0; j < 4; ++j)
                    acc[m][j] = __builtin_amdgcn_mfma_i32_16x16x64_i8(a[m], b[j], acc[m][j], 0, 0, 0);
        }
    }

    // Epilogue: out_i = acc + 2*bias; f = out_i * (0.05*ws/0.1) + 5; rint; clamp; int32 store.
    // C/D frag: col (cout) = lane&15, row (pixel) = grp*4 + reg.
    float sc[4];
    int b2[4];
#pragma unroll
    for (int j = 0; j < 4; ++j) {
        int cout = nb * 64 + j * 16 + row;
        sc[j] = wscale[cout] * 0.5f;          // 0.05/0.1 * ws
        b2[j] = 2 * bias[cout];
    }
#pragma unroll
    for (int m = 0; m < 4; ++m) {
        int pix = pbase + m * 16 + grp * 4;          // pixel of reg 0
        int local = pix - n * PIX_PER_IMG;           // h*56 + w
        size_t obase = (size_t)n * (COUT * PIX_PER_IMG) + local;
#pragma unroll
        for (int j = 0; j < 4; ++j) {
            int cout = nb * 64 + j * 16 + row;
            i32x4 v;
#pragma unroll
            for (int r = 0; r < 4; ++r) {
                int o = acc[m][j][r] + b2[j];
                float f = fmaf((float)o, sc[j], 5.0f);
                f = rintf(f);                         // RNE == jnp.round
                f = fminf(fmaxf(f, -128.0f), 127.0f);
                v[r] = (int)f;
            }
            __builtin_nontemporal_store(v, (i32x4*)(out + obase + (size_t)cout * PIX_PER_IMG));
        }
    }
}

extern "C" void kernel_launch(void* const* d_in, const int* in_sizes, int n_in,
                              void* d_out, int out_size, void* d_ws, size_t ws_size,
                              hipStream_t stream) {
    const int* x = (const int*)d_in[0];
    const int* w = (const int*)d_in[1];
    const int* bias = (const int*)d_in[2];
    const float* ws = (const float*)d_in[3];
    int* out = (int*)d_out;

    signed char* xq = (signed char*)d_ws;
    signed char* wq = xq + XQ_BYTES;          // 288 KB fragment-ordered weights

    pack_x_kernel<<<NB_N * HH, 256, 0, stream>>>(x, xq);
    pack_w_kernel<<<72, 256, 0, stream>>>(w, wq);
    conv_kernel<<<(TOTAL_PIX / 256) * 4, 256, 0, stream>>>(xq, wq, bias, ws, out);
}